// Round 2
// baseline (1009.457 us; speedup 1.0000x reference)
//
#include <hip/hip_runtime.h>

#define NN 50000
#define EE 1600000
#define ETOT (EE + NN)
#define INDIM 1280
#define HID 256
#define HEADS 4
#define DHD 64
#define NCLS 6
#define NEG 0.2f
#define LNEPS 1e-5f

typedef __attribute__((ext_vector_type(8))) short short8;
typedef __attribute__((ext_vector_type(4))) float floatx4;

__device__ __forceinline__ unsigned short f2b(float f) {
    unsigned int u = __float_as_uint(f);
    u += 0x7FFF + ((u >> 16) & 1);
    return (unsigned short)(u >> 16);
}
__device__ __forceinline__ float b2f(unsigned short b) {
    return __uint_as_float(((unsigned int)b) << 16);
}

// s_waitcnt lgkmcnt(0), vmcnt/expcnt no-wait
#define WAIT_LGKM0() __builtin_amdgcn_s_waitcnt(0xC07F)

// ---------------- CSR build ----------------
__global__ void init_cnt_kernel(int* __restrict__ cnt) {
    int n = blockIdx.x * 256 + threadIdx.x;
    if (n < NN) cnt[n] = 1;  // self loop
}

__global__ void count_edges_kernel(const int* __restrict__ dst, int* __restrict__ cnt) {
    int e = blockIdx.x * 256 + threadIdx.x;
    if (e < EE) atomicAdd(&cnt[dst[e]], 1);
}

__global__ __launch_bounds__(1024) void scan1_kernel(const int* __restrict__ cnt,
                                                     int* __restrict__ scanned,
                                                     int* __restrict__ chtot, int n) {
    __shared__ int wsum[16];
    int tid = threadIdx.x, lane = tid & 63, wv = tid >> 6;
    int i = blockIdx.x * 1024 + tid;
    int s = (i < n) ? cnt[i] : 0;
#pragma unroll
    for (int off = 1; off < 64; off <<= 1) {
        int t = __shfl_up(s, off, 64);
        if (lane >= off) s += t;
    }
    if (lane == 63) wsum[wv] = s;
    __syncthreads();
    if (tid < 16) {
        int ws = wsum[tid];
#pragma unroll
        for (int off = 1; off < 16; off <<= 1) {
            int t = __shfl_up(ws, off, 16);
            if (tid >= off) ws += t;
        }
        wsum[tid] = ws;
    }
    __syncthreads();
    s += (wv > 0) ? wsum[wv - 1] : 0;
    if (i < n) scanned[i] = s;
    if (tid == 1023) chtot[blockIdx.x] = s;
}

__global__ void scan2_kernel(int* __restrict__ chtot, int nch) {
    int lane = threadIdx.x;
    int v = (lane < nch) ? chtot[lane] : 0;
#pragma unroll
    for (int off = 1; off < 64; off <<= 1) {
        int t = __shfl_up(v, off, 64);
        if (lane >= off) v += t;
    }
    if (lane < nch) chtot[lane] = v;
}

__global__ void scan3_kernel(const int* __restrict__ scanned, const int* __restrict__ chtot,
                             int* __restrict__ rowptr, int n) {
    int i = blockIdx.x * 256 + threadIdx.x;
    if (i == 0) rowptr[0] = 0;
    if (i < n) {
        int ch = i >> 10;
        rowptr[i + 1] = scanned[i] + (ch ? chtot[ch - 1] : 0);
    }
}

__global__ void copyfill_kernel(const int* __restrict__ rowptr, int* __restrict__ cursor,
                                int* __restrict__ csr, int* __restrict__ edst) {
    int n = blockIdx.x * 256 + threadIdx.x;
    if (n < NN) {
        int p = rowptr[n];
        csr[p] = n;
        edst[p] = n;
        cursor[n] = p + 1;
    }
}

__global__ void scatter_edges_kernel(const int* __restrict__ src, const int* __restrict__ dst,
                                     int* __restrict__ cursor, int* __restrict__ csr,
                                     int* __restrict__ edst) {
    int e = blockIdx.x * 256 + threadIdx.x;
    if (e < EE) {
        int d = dst[e];
        int pos = atomicAdd(&cursor[d], 1);
        csr[pos] = src[e];
        edst[pos] = d;
    }
}

// ---------------- per-layer edge softmax numerators (hoisted out of agg loop) ----------------
// w[pos][head] = exp(leaky_relu(al_s[src] + al_d[dst])); denominators summed later in agg.
__global__ void edge_w_kernel(const int* __restrict__ csr, const int* __restrict__ edst,
                              const float* __restrict__ al_s, const float* __restrict__ al_d,
                              float* __restrict__ w) {
    int e = blockIdx.x * 256 + threadIdx.x;
    if (e >= ETOT) return;
    int s = csr[e], d = edst[e];
    float4 as = *(const float4*)&al_s[(size_t)s * 4];
    float4 ad = *(const float4*)&al_d[(size_t)d * 4];
    float e0 = as.x + ad.x; e0 = e0 > 0.f ? e0 : NEG * e0;
    float e1 = as.y + ad.y; e1 = e1 > 0.f ? e1 : NEG * e1;
    float e2 = as.z + ad.z; e2 = e2 > 0.f ? e2 : NEG * e2;
    float e3 = as.w + ad.w; e3 = e3 > 0.f ? e3 : NEG * e3;
    float4 wv = make_float4(__expf(e0), __expf(e1), __expf(e2), __expf(e3));
    *(float4*)&w[(size_t)e * 4] = wv;
}

// ---------------- weight pack: W[K][N] fp32 -> MFMA B-fragment order bf16 ----------------
__global__ void pack_w_kernel(const float* __restrict__ W, unsigned short* __restrict__ out,
                              int K, int N) {
    int idx = blockIdx.x * 256 + threadIdx.x;
    int total = (K >> 6) * (N >> 4) * 2 * 64;
    if (idx >= total) return;
    int ln = idx & 63;
    int t = idx >> 6;
    int ks = t & 1; t >>= 1;
    int NT = N >> 4;
    int nt = t % NT, kc = t / NT;
    int n = nt * 16 + (ln & 15);
    int k = kc * 64 + ks * 32 + ((ln >> 4) << 3);
    unsigned short u[8];
#pragma unroll
    for (int j = 0; j < 8; j++) u[j] = f2b(W[(size_t)(k + j) * N + n]);
    *(int4*)&out[(size_t)idx * 8] = *(const int4*)u;
}

// ---------------- pipelined LDS-dbuf MFMA GEMM w/ fused epilogues ----------------
// PROJ (NT=16): also emit al_s/al_d attention logits from fp32 acc.
// CLS  (NT=8):  skip C store entirely; emit 6-class logits = relu(acc+bias) @ W2 + b2.
template <int AF32, int KI, int NT, int ACT, int WF32, int WB16, int PROJ, int CLS>
__global__ __launch_bounds__(256) void pgemm_kernel(const float* __restrict__ Af,
                                                    const unsigned short* __restrict__ Ab,
                                                    const unsigned short* __restrict__ Bf,
                                                    const float* __restrict__ bias,
                                                    float* __restrict__ Cf,
                                                    unsigned short* __restrict__ Cb,
                                                    const float* __restrict__ aps,
                                                    const float* __restrict__ apd,
                                                    float* __restrict__ als,
                                                    float* __restrict__ ald,
                                                    const float* __restrict__ W2,
                                                    const float* __restrict__ b2,
                                                    float* __restrict__ out2,
                                                    int M) {
    constexpr int NW = NT / 4;
    constexpr int K = KI * 64;
    __shared__ __align__(16) unsigned short Als[2][4096];  // 2 x 8KB bf16 64x64 tiles
    int tid = threadIdx.x, wv = tid >> 6, ln = tid & 63;
    int m0 = blockIdx.x * 64;

    int srow[2], scol[2];
#pragma unroll
    for (int i = 0; i < 2; i++) {
        int s = tid + i * 256;
        int r = s >> 3;
        srow[i] = min(m0 + r, M - 1);
        scol[i] = ((s & 7) ^ (r & 7)) * 8;
    }

    floatx4 acc[4][NW] = {};
    short8 breg[2][NW * 2];
    float4 af0[4], af1[4];
    int4 ai0[2], ai1[2];

    auto issueA = [&](int k, float4* af, int4* ai) {
#pragma unroll
        for (int i = 0; i < 2; i++) {
            if (AF32) {
                const float* p = Af + (size_t)srow[i] * K + k * 64 + scol[i];
                af[i * 2] = *(const float4*)p;
                af[i * 2 + 1] = *(const float4*)(p + 4);
            } else {
                ai[i] = *(const int4*)(Ab + (size_t)srow[i] * K + k * 64 + scol[i]);
            }
        }
    };
    auto issueB = [&](int k, short8* b) {
#pragma unroll
        for (int nw = 0; nw < NW; nw++)
#pragma unroll
            for (int ks = 0; ks < 2; ks++)
                b[nw * 2 + ks] = *(const short8*)(
                    Bf + ((((size_t)k * NT + (wv * NW + nw)) * 2 + ks) * 64 + ln) * 8);
    };
    auto writeA = [&](int k, const float4* af, const int4* ai) {
        unsigned short* dst = &Als[k & 1][0];
#pragma unroll
        for (int i = 0; i < 2; i++) {
            int4 v;
            if (AF32) {
                unsigned short u[8] = {f2b(af[2 * i].x), f2b(af[2 * i].y),
                                       f2b(af[2 * i].z), f2b(af[2 * i].w),
                                       f2b(af[2 * i + 1].x), f2b(af[2 * i + 1].y),
                                       f2b(af[2 * i + 1].z), f2b(af[2 * i + 1].w)};
                v = *(const int4*)u;
            } else {
                v = ai[i];
            }
            *(int4*)&dst[(tid + i * 256) * 8] = v;
        }
    };
    auto compute = [&](int k, const short8* b) {
        const unsigned short* src = &Als[k & 1][0];
#pragma unroll
        for (int ks = 0; ks < 2; ks++) {
            short8 a[4];
#pragma unroll
            for (int mt = 0; mt < 4; mt++) {
                int row = mt * 16 + (ln & 15);
                int g = ks * 4 + (ln >> 4);
                int off8 = (row >> 3) * 512 + (row & 7) * 64 + (g ^ (row & 7)) * 8;
                a[mt] = *(const short8*)&src[off8];
            }
#pragma unroll
            for (int nw = 0; nw < NW; nw++)
#pragma unroll
                for (int mt = 0; mt < 4; mt++)
                    acc[mt][nw] = __builtin_amdgcn_mfma_f32_16x16x32_bf16(
                        a[mt], b[nw * 2 + ks], acc[mt][nw], 0, 0, 0);
        }
    };

    issueA(0, af0, ai0);
    issueB(0, breg[0]);
    writeA(0, af0, ai0);
    WAIT_LGKM0();
    __builtin_amdgcn_s_barrier();

#pragma unroll
    for (int kk = 0; kk < KI / 2; kk++) {
        int k = kk * 2;
        issueA(k + 1, af1, ai1);
        issueB(k + 1, breg[1]);
        compute(k, breg[0]);
        writeA(k + 1, af1, ai1);
        WAIT_LGKM0();
        __builtin_amdgcn_s_barrier();
        if (k + 2 < KI) {
            issueA(k + 2, af0, ai0);
            issueB(k + 2, breg[0]);
        }
        compute(k + 1, breg[1]);
        if (k + 2 < KI) {
            writeA(k + 2, af0, ai0);
            WAIT_LGKM0();
            __builtin_amdgcn_s_barrier();
        }
    }

    constexpr int Nout = NT * 16;
    // main C store (C/D layout: col=lane&15, row=(lane>>4)*4+reg)
    if constexpr (WF32 || WB16) {
#pragma unroll
        for (int mt = 0; mt < 4; mt++) {
#pragma unroll
            for (int nw = 0; nw < NW; nw++) {
                int col = (wv * NW + nw) * 16 + (ln & 15);
                int rb = m0 + mt * 16 + (ln >> 4) * 4;
                float bi = bias ? bias[col] : 0.f;
#pragma unroll
                for (int r = 0; r < 4; r++) {
                    int row = rb + r;
                    if (row < M) {
                        float v = acc[mt][nw][r] + bi;
                        if (ACT) v = fmaxf(v, 0.f);
                        if (WF32) Cf[(size_t)row * Nout + col] = v;
                        if (WB16) Cb[(size_t)row * Nout + col] = f2b(v);
                    }
                }
            }
        }
    }

    // fused attention-logit projection: wave wv == head wv (cols wv*64..wv*64+63)
    if constexpr (PROJ) {
        float avs[NW], avd[NW];
#pragma unroll
        for (int nw = 0; nw < NW; nw++) {
            int d = nw * 16 + (ln & 15);
            avs[nw] = aps[wv * DHD + d];
            avd[nw] = apd[wv * DHD + d];
        }
#pragma unroll
        for (int mt = 0; mt < 4; mt++) {
#pragma unroll
            for (int r = 0; r < 4; r++) {
                float ssum = 0.f, dsum = 0.f;
#pragma unroll
                for (int nw = 0; nw < NW; nw++) {
                    float v = acc[mt][nw][r];
                    ssum = fmaf(v, avs[nw], ssum);
                    dsum = fmaf(v, avd[nw], dsum);
                }
#pragma unroll
                for (int m = 8; m > 0; m >>= 1) {
                    ssum += __shfl_xor(ssum, m, 16);
                    dsum += __shfl_xor(dsum, m, 16);
                }
                int row = m0 + mt * 16 + (ln >> 4) * 4 + r;
                if ((ln & 15) == 0 && row < M) {
                    als[row * 4 + wv] = ssum;
                    ald[row * 4 + wv] = dsum;
                }
            }
        }
    }

    // fused tiny classifier: logits = relu(acc+bias) @ W2[Nout][6] + b2
    if constexpr (CLS) {
        __shared__ float cred[64][4][NCLS];
        float w2[NW][NCLS];
#pragma unroll
        for (int nw = 0; nw < NW; nw++) {
            int col = (wv * NW + nw) * 16 + (ln & 15);
#pragma unroll
            for (int c = 0; c < NCLS; c++) w2[nw][c] = W2[col * NCLS + c];
        }
#pragma unroll
        for (int mt = 0; mt < 4; mt++) {
#pragma unroll
            for (int r = 0; r < 4; r++) {
                float p[NCLS] = {};
#pragma unroll
                for (int nw = 0; nw < NW; nw++) {
                    int col = (wv * NW + nw) * 16 + (ln & 15);
                    float v = fmaxf(acc[mt][nw][r] + bias[col], 0.f);
#pragma unroll
                    for (int c = 0; c < NCLS; c++) p[c] = fmaf(v, w2[nw][c], p[c]);
                }
#pragma unroll
                for (int m = 8; m > 0; m >>= 1)
#pragma unroll
                    for (int c = 0; c < NCLS; c++) p[c] += __shfl_xor(p[c], m, 16);
                int rl = mt * 16 + (ln >> 4) * 4 + r;
                if ((ln & 15) == 0)
#pragma unroll
                    for (int c = 0; c < NCLS; c++) cred[rl][wv][c] = p[c];
            }
        }
        __syncthreads();
        for (int t = tid; t < 64 * NCLS; t += 256) {
            int row = t / NCLS, c = t % NCLS;
            if (m0 + row < M) {
                float s = cred[row][0][c] + cred[row][1][c] + cred[row][2][c] +
                          cred[row][3][c] + b2[c];
                out2[(size_t)(m0 + row) * NCLS + c] = s;
            }
        }
    }
}

// ---------------- wave-per-node aggregation + LN + ReLU + residual ----------------
// Edge weights precomputed by edge_w_kernel (contiguous stream). Inner loop per edge:
// broadcast csr[i] -> 512B row gather -> fma; 4 edges per half-wave (8/wave, 4KB) in flight.
// Denominator accumulated from the contiguous w stream, normalized once in the epilogue.
__global__ __launch_bounds__(256) void agg_ln_kernel(const int* __restrict__ rowptr,
                                                     const int* __restrict__ csr,
                                                     const float* __restrict__ wgt,
                                                     const unsigned short* __restrict__ xhb,
                                                     const float* __restrict__ bgat,
                                                     const float* __restrict__ g,
                                                     const float* __restrict__ bb,
                                                     float* __restrict__ h,
                                                     unsigned short* __restrict__ hb) {
    int wv = threadIdx.x >> 6, ln = threadIdx.x & 63;
    int n = blockIdx.x * 4 + wv;
    if (n >= NN) return;
    int start = rowptr[n], end = rowptr[n + 1];
    int half = ln >> 5;   // edge-parity this lane handles
    int j = ln & 31;      // feature-dim group: dims j*8..j*8+7
    int head = j >> 3;    // 0..3

    float p[8] = {}, q[8] = {};
    float dsp = 0.f, dsq = 0.f;

    int i = start + half;
    for (; i + 6 < end; i += 8) {
        int s0 = csr[i], s1 = csr[i + 2], s2 = csr[i + 4], s3 = csr[i + 6];
        float w0 = wgt[(size_t)i * 4 + head];
        float w1 = wgt[(size_t)(i + 2) * 4 + head];
        float w2 = wgt[(size_t)(i + 4) * 4 + head];
        float w3 = wgt[(size_t)(i + 6) * 4 + head];
        short8 u0 = *(const short8*)&xhb[(size_t)s0 * HID + j * 8];
        short8 u1 = *(const short8*)&xhb[(size_t)s1 * HID + j * 8];
        short8 u2 = *(const short8*)&xhb[(size_t)s2 * HID + j * 8];
        short8 u3 = *(const short8*)&xhb[(size_t)s3 * HID + j * 8];
        dsp += w0 + w2;
        dsq += w1 + w3;
#pragma unroll
        for (int k = 0; k < 8; k++) {
            p[k] = fmaf(w0, b2f((unsigned short)u0[k]), p[k]);
            q[k] = fmaf(w1, b2f((unsigned short)u1[k]), q[k]);
        }
#pragma unroll
        for (int k = 0; k < 8; k++) {
            p[k] = fmaf(w2, b2f((unsigned short)u2[k]), p[k]);
            q[k] = fmaf(w3, b2f((unsigned short)u3[k]), q[k]);
        }
    }
    for (; i < end; i += 2) {
        int s0 = csr[i];
        float w0 = wgt[(size_t)i * 4 + head];
        short8 u0 = *(const short8*)&xhb[(size_t)s0 * HID + j * 8];
        dsp += w0;
#pragma unroll
        for (int k = 0; k < 8; k++) p[k] = fmaf(w0, b2f((unsigned short)u0[k]), p[k]);
    }

    // combine the two edge-parity halves (per-head denominator + per-dim sums)
    float ds = dsp + dsq;
    ds += __shfl_xor(ds, 32, 64);
    float inv = 1.f / ds;

    const float4* bgp = (const float4*)&bgat[j * 8];
    float4 bg0 = bgp[0], bg1 = bgp[1];
    float bgk[8] = {bg0.x, bg0.y, bg0.z, bg0.w, bg1.x, bg1.y, bg1.z, bg1.w};

    float vv[8];
    float ps = 0.f, ps2 = 0.f;
#pragma unroll
    for (int k = 0; k < 8; k++) {
        float t = p[k] + q[k];
        t += __shfl_xor(t, 32, 64);
        float val = t * inv + bgk[k];
        vv[k] = val;
        ps += val;
        ps2 = fmaf(val, val, ps2);
    }
    // wave LN reduce: halves are identical after the 32-swap, reduce within 32 lanes
#pragma unroll
    for (int off = 16; off > 0; off >>= 1) {
        ps += __shfl_xor(ps, off, 64);
        ps2 += __shfl_xor(ps2, off, 64);
    }
    float mu = ps * (1.f / HID);
    float var = ps2 * (1.f / HID) - mu * mu;
    float rs = rsqrtf(var + LNEPS);

    const float4* gp = (const float4*)&g[j * 8];
    const float4* bp = (const float4*)&bb[j * 8];
    float4 g0 = gp[0], g1 = gp[1];
    float4 c0 = bp[0], c1 = bp[1];
    float gk[8] = {g0.x, g0.y, g0.z, g0.w, g1.x, g1.y, g1.z, g1.w};
    float ck[8] = {c0.x, c0.y, c0.z, c0.w, c1.x, c1.y, c1.z, c1.w};

    size_t idx = (size_t)n * HID + j * 8;
    const float4* hp = (const float4*)&h[idx];
    float4 h0 = hp[0], h1 = hp[1];
    float hk[8] = {h0.x, h0.y, h0.z, h0.w, h1.x, h1.y, h1.z, h1.w};

    float nh[8];
#pragma unroll
    for (int k = 0; k < 8; k++) {
        float o = fmaxf((vv[k] - mu) * rs * gk[k] + ck[k], 0.f);
        nh[k] = hk[k] + o;
    }

    if (half == 0) {
        ((float4*)&h[idx])[0] = make_float4(nh[0], nh[1], nh[2], nh[3]);
        ((float4*)&h[idx])[1] = make_float4(nh[4], nh[5], nh[6], nh[7]);
    } else {
        unsigned short ub[8];
#pragma unroll
        for (int k = 0; k < 8; k++) ub[k] = f2b(nh[k]);
        *(int4*)&hb[idx] = *(const int4*)ub;
    }
}

extern "C" void kernel_launch(void* const* d_in, const int* in_sizes, int n_in,
                              void* d_out, int out_size, void* d_ws, size_t ws_size,
                              hipStream_t stream) {
    const float* x    = (const float*)d_in[0];
    const int*   ei   = (const int*)d_in[1];
    const float* W_in = (const float*)d_in[2];
    const float* b_in = (const float*)d_in[3];
    const float* W_gat[2]   = {(const float*)d_in[4],  (const float*)d_in[10]};
    const float* att_src[2] = {(const float*)d_in[5],  (const float*)d_in[11]};
    const float* att_dst[2] = {(const float*)d_in[6],  (const float*)d_in[12]};
    const float* b_gat[2]   = {(const float*)d_in[7],  (const float*)d_in[13]};
    const float* ln_g[2]    = {(const float*)d_in[8],  (const float*)d_in[14]};
    const float* ln_b[2]    = {(const float*)d_in[9],  (const float*)d_in[15]};
    const float* W_c1 = (const float*)d_in[16];
    const float* b_c1 = (const float*)d_in[17];
    const float* W_c2 = (const float*)d_in[18];
    const float* b_c2 = (const float*)d_in[19];

    char* ws = (char*)d_ws;
    size_t off = 0;
    auto alloc = [&](size_t bytes) -> void* {
        void* p = ws + off;
        off += (bytes + 255) & ~(size_t)255;
        return p;
    };
    float*          h   = (float*)alloc((size_t)NN * HID * 4);
    unsigned short* hb  = (unsigned short*)alloc((size_t)NN * HID * 2);
    unsigned short* xhb = (unsigned short*)alloc((size_t)NN * HID * 2);
    float* al_s = (float*)alloc((size_t)NN * HEADS * 4);
    float* al_d = (float*)alloc((size_t)NN * HEADS * 4);
    int* rowptr  = (int*)alloc((size_t)(NN + 1) * 4);
    int* cursor  = (int*)alloc((size_t)NN * 4);
    int* csr     = (int*)alloc((size_t)ETOT * 4);
    int* edst    = (int*)alloc((size_t)ETOT * 4);
    float* wgt   = (float*)alloc((size_t)ETOT * HEADS * 4);
    int* scanned = (int*)alloc((size_t)NN * 4);
    int* chtot   = (int*)alloc(64 * 4);
    unsigned short* WinF = (unsigned short*)alloc((size_t)HID * INDIM * 2);
    unsigned short* WgF0 = (unsigned short*)alloc((size_t)HID * HID * 2);
    unsigned short* WgF1 = (unsigned short*)alloc((size_t)HID * HID * 2);
    unsigned short* Wc1F = (unsigned short*)alloc((size_t)(HID / 2) * HID * 2);
    unsigned short* WgF[2] = {WgF0, WgF1};

    const int* srcv = ei;
    const int* dstv = ei + EE;

    // weight packs (fp32 [K][N] -> bf16 MFMA B-fragment order)
    pack_w_kernel<<<(INDIM * HID / 8 + 255) / 256, 256, 0, stream>>>(W_in, WinF, INDIM, HID);
    pack_w_kernel<<<(HID * HID / 8 + 255) / 256, 256, 0, stream>>>(W_gat[0], WgF0, HID, HID);
    pack_w_kernel<<<(HID * HID / 8 + 255) / 256, 256, 0, stream>>>(W_gat[1], WgF1, HID, HID);
    pack_w_kernel<<<(HID * (HID / 2) / 8 + 255) / 256, 256, 0, stream>>>(W_c1, Wc1F, HID, HID / 2);

    // CSR build
    int nch = (NN + 1023) / 1024;
    init_cnt_kernel<<<(NN + 255) / 256, 256, 0, stream>>>(cursor);
    count_edges_kernel<<<(EE + 255) / 256, 256, 0, stream>>>(dstv, cursor);
    scan1_kernel<<<nch, 1024, 0, stream>>>(cursor, scanned, chtot, NN);
    scan2_kernel<<<1, 64, 0, stream>>>(chtot, nch);
    scan3_kernel<<<(NN + 255) / 256, 256, 0, stream>>>(scanned, chtot, rowptr, NN);
    copyfill_kernel<<<(NN + 255) / 256, 256, 0, stream>>>(rowptr, cursor, csr, edst);
    scatter_edges_kernel<<<(EE + 255) / 256, 256, 0, stream>>>(srcv, dstv, cursor, csr, edst);

    int MB64 = (NN + 63) / 64;  // 782

    // h = relu(x @ W_in + b_in): fp32 A, KI=20
    pgemm_kernel<1, 20, 16, 1, 1, 1, 0, 0><<<MB64, 256, 0, stream>>>(
        x, nullptr, WinF, b_in, h, hb,
        nullptr, nullptr, nullptr, nullptr, nullptr, nullptr, nullptr, NN);

    for (int l = 0; l < 2; l++) {
        // xh = h @ W_gat (bf16 out) + fused al_src/al_dst projection
        pgemm_kernel<0, 4, 16, 0, 0, 1, 1, 0><<<MB64, 256, 0, stream>>>(
            nullptr, hb, WgF[l], nullptr, nullptr, xhb,
            att_src[l], att_dst[l], al_s, al_d, nullptr, nullptr, nullptr, NN);
        edge_w_kernel<<<(ETOT + 255) / 256, 256, 0, stream>>>(csr, edst, al_s, al_d, wgt);
        agg_ln_kernel<<<(NN + 3) / 4, 256, 0, stream>>>(rowptr, csr, wgt, xhb,
                                                        b_gat[l], ln_g[l], ln_b[l], h, hb);
    }

    // classifier: logits = relu(h @ W_c1 + b_c1) @ W_c2 + b_c2, fully fused
    pgemm_kernel<0, 4, 8, 1, 0, 0, 0, 1><<<MB64, 256, 0, stream>>>(
        nullptr, hb, Wc1F, b_c1, nullptr, nullptr,
        nullptr, nullptr, nullptr, nullptr, W_c2, b_c2, (float*)d_out, NN);
}

// Round 3
// 991.796 us; speedup vs baseline: 1.0178x; 1.0178x over previous
//
#include <hip/hip_runtime.h>

#define NN 50000
#define EE 1600000
#define INDIM 1280
#define HID 256
#define HEADS 4
#define DHD 64
#define NCLS 6
#define NEG 0.2f
#define LNEPS 1e-5f

typedef __attribute__((ext_vector_type(8))) short short8;
typedef __attribute__((ext_vector_type(4))) float floatx4;

__device__ __forceinline__ unsigned short f2b(float f) {
    unsigned int u = __float_as_uint(f);
    u += 0x7FFF + ((u >> 16) & 1);
    return (unsigned short)(u >> 16);
}
__device__ __forceinline__ float b2f(unsigned short b) {
    return __uint_as_float(((unsigned int)b) << 16);
}

// s_waitcnt lgkmcnt(0), vmcnt/expcnt no-wait
#define WAIT_LGKM0() __builtin_amdgcn_s_waitcnt(0xC07F)

// ---------------- CSR build ----------------
__global__ void init_cnt_kernel(int* __restrict__ cnt) {
    int n = blockIdx.x * 256 + threadIdx.x;
    if (n < NN) cnt[n] = 1;  // self loop
}

__global__ void count_edges_kernel(const int* __restrict__ dst, int* __restrict__ cnt) {
    int e = blockIdx.x * 256 + threadIdx.x;
    if (e < EE) atomicAdd(&cnt[dst[e]], 1);
}

__global__ __launch_bounds__(1024) void scan1_kernel(const int* __restrict__ cnt,
                                                     int* __restrict__ scanned,
                                                     int* __restrict__ chtot, int n) {
    __shared__ int wsum[16];
    int tid = threadIdx.x, lane = tid & 63, wv = tid >> 6;
    int i = blockIdx.x * 1024 + tid;
    int s = (i < n) ? cnt[i] : 0;
#pragma unroll
    for (int off = 1; off < 64; off <<= 1) {
        int t = __shfl_up(s, off, 64);
        if (lane >= off) s += t;
    }
    if (lane == 63) wsum[wv] = s;
    __syncthreads();
    if (tid < 16) {
        int ws = wsum[tid];
#pragma unroll
        for (int off = 1; off < 16; off <<= 1) {
            int t = __shfl_up(ws, off, 16);
            if (tid >= off) ws += t;
        }
        wsum[tid] = ws;
    }
    __syncthreads();
    s += (wv > 0) ? wsum[wv - 1] : 0;
    if (i < n) scanned[i] = s;
    if (tid == 1023) chtot[blockIdx.x] = s;
}

__global__ void scan2_kernel(int* __restrict__ chtot, int nch) {
    int lane = threadIdx.x;
    int v = (lane < nch) ? chtot[lane] : 0;
#pragma unroll
    for (int off = 1; off < 64; off <<= 1) {
        int t = __shfl_up(v, off, 64);
        if (lane >= off) v += t;
    }
    if (lane < nch) chtot[lane] = v;
}

__global__ void scan3_kernel(const int* __restrict__ scanned, const int* __restrict__ chtot,
                             int* __restrict__ rowptr, int n) {
    int i = blockIdx.x * 256 + threadIdx.x;
    if (i == 0) rowptr[0] = 0;
    if (i < n) {
        int ch = i >> 10;
        rowptr[i + 1] = scanned[i] + (ch ? chtot[ch - 1] : 0);
    }
}

__global__ void copyfill_kernel(const int* __restrict__ rowptr, int* __restrict__ cursor,
                                int* __restrict__ csr) {
    int n = blockIdx.x * 256 + threadIdx.x;
    if (n < NN) {
        int p = rowptr[n];
        csr[p] = n;
        cursor[n] = p + 1;
    }
}

__global__ void scatter_edges_kernel(const int* __restrict__ src, const int* __restrict__ dst,
                                     int* __restrict__ cursor, int* __restrict__ csr) {
    int e = blockIdx.x * 256 + threadIdx.x;
    if (e < EE) {
        int d = dst[e];
        int pos = atomicAdd(&cursor[d], 1);
        csr[pos] = src[e];
    }
}

// ---------------- weight pack: W[K][N] fp32 -> MFMA B-fragment order bf16 ----------------
__global__ void pack_w_kernel(const float* __restrict__ W, unsigned short* __restrict__ out,
                              int K, int N) {
    int idx = blockIdx.x * 256 + threadIdx.x;
    int total = (K >> 6) * (N >> 4) * 2 * 64;
    if (idx >= total) return;
    int ln = idx & 63;
    int t = idx >> 6;
    int ks = t & 1; t >>= 1;
    int NT = N >> 4;
    int nt = t % NT, kc = t / NT;
    int n = nt * 16 + (ln & 15);
    int k = kc * 64 + ks * 32 + ((ln >> 4) << 3);
    unsigned short u[8];
#pragma unroll
    for (int j = 0; j < 8; j++) u[j] = f2b(W[(size_t)(k + j) * N + n]);
    *(int4*)&out[(size_t)idx * 8] = *(const int4*)u;
}

// ---------------- dedicated in-proj GEMM: MT=128 rows/block, fp32 A -> bf16, N=256 ----------------
// Single-buffered af/breg with WAR-ordered reissue: A-loads for k+1 issued right after
// writeA(k) consumed the regs, flying across the raw s_barrier (vmcnt NOT drained there).
// 64 MFMA per barrier per wave; 2x16KB LDS dbuf; 391 blocks all co-resident.
__global__ __launch_bounds__(256) void inproj_kernel(const float* __restrict__ Af,
                                                     const unsigned short* __restrict__ Bf,
                                                     const float* __restrict__ bias,
                                                     float* __restrict__ Cf,
                                                     unsigned short* __restrict__ Cb) {
    constexpr int KI = 20;  // K = 1280 = 20 x 64
    __shared__ __align__(16) unsigned short Als[2][8192];  // 2 x 16KB bf16 128x64 tiles
    int tid = threadIdx.x, wv = tid >> 6, ln = tid & 63;
    int m0 = blockIdx.x * 128;

    int srow[4], scol[4];
#pragma unroll
    for (int i = 0; i < 4; i++) {
        int s = tid + i * 256;
        int r = s >> 3;
        srow[i] = min(m0 + r, NN - 1);
        scol[i] = ((s & 7) ^ (r & 7)) * 8;
    }

    floatx4 acc[8][4] = {};
    short8 breg[8];
    float4 af[8];

    auto issueA = [&](int k) {
#pragma unroll
        for (int i = 0; i < 4; i++) {
            const float* p = Af + (size_t)srow[i] * INDIM + k * 64 + scol[i];
            af[i * 2] = *(const float4*)p;
            af[i * 2 + 1] = *(const float4*)(p + 4);
        }
    };
    auto issueB = [&](int k) {
#pragma unroll
        for (int nw = 0; nw < 4; nw++)
#pragma unroll
            for (int ks = 0; ks < 2; ks++)
                breg[nw * 2 + ks] = *(const short8*)(
                    Bf + ((((size_t)k * 16 + (wv * 4 + nw)) * 2 + ks) * 64 + ln) * 8);
    };
    auto writeA = [&](int k) {
        unsigned short* dst = &Als[k & 1][0];
#pragma unroll
        for (int i = 0; i < 4; i++) {
            unsigned short u[8] = {f2b(af[2 * i].x), f2b(af[2 * i].y),
                                   f2b(af[2 * i].z), f2b(af[2 * i].w),
                                   f2b(af[2 * i + 1].x), f2b(af[2 * i + 1].y),
                                   f2b(af[2 * i + 1].z), f2b(af[2 * i + 1].w)};
            *(int4*)&dst[(tid + i * 256) * 8] = *(const int4*)u;
        }
    };
    auto compute = [&](int k) {
        const unsigned short* src = &Als[k & 1][0];
#pragma unroll
        for (int ks = 0; ks < 2; ks++) {
            short8 a[8];
#pragma unroll
            for (int mt = 0; mt < 8; mt++) {
                int row = mt * 16 + (ln & 15);
                int g = ks * 4 + (ln >> 4);
                a[mt] = *(const short8*)&src[row * 64 + (g ^ (row & 7)) * 8];
            }
#pragma unroll
            for (int nw = 0; nw < 4; nw++)
#pragma unroll
                for (int mt = 0; mt < 8; mt++)
                    acc[mt][nw] = __builtin_amdgcn_mfma_f32_16x16x32_bf16(
                        a[mt], breg[nw * 2 + ks], acc[mt][nw], 0, 0, 0);
        }
    };

    issueA(0);
    writeA(0);       // waits on k=0 A-loads
    issueA(1);       // k=1 loads fly across barrier + compute(0)
    issueB(0);
    WAIT_LGKM0();
    __builtin_amdgcn_s_barrier();

    for (int k = 0; k < KI; k++) {
        compute(k);                       // consumes Als[k&1], breg(k)
        if (k + 1 < KI) {
            issueB(k + 1);                // WAR: breg free after compute(k)
            writeA(k + 1);                // af(k+1) loads had full compute(k) of cover
        }
        if (k + 2 < KI) issueA(k + 2);    // WAR: af free after writeA(k+1)
        if (k + 1 < KI) {
            WAIT_LGKM0();                 // ds_writes visible; vmcnt NOT drained
            __builtin_amdgcn_s_barrier();
        }
    }

    // epilogue: relu(acc + bias) -> h fp32 + hb bf16
#pragma unroll
    for (int mt = 0; mt < 8; mt++) {
#pragma unroll
        for (int nw = 0; nw < 4; nw++) {
            int col = (wv * 4 + nw) * 16 + (ln & 15);
            int rb = m0 + mt * 16 + (ln >> 4) * 4;
            float bi = bias[col];
#pragma unroll
            for (int r = 0; r < 4; r++) {
                int row = rb + r;
                if (row < NN) {
                    float v = fmaxf(acc[mt][nw][r] + bi, 0.f);
                    Cf[(size_t)row * HID + col] = v;
                    Cb[(size_t)row * HID + col] = f2b(v);
                }
            }
        }
    }
}

// ---------------- pipelined LDS-dbuf MFMA GEMM w/ fused epilogues (bf16 A) ----------------
// PROJ (NT=16): also emit al_s/al_d attention logits from fp32 acc.
// CLS  (NT=8):  skip C store entirely; emit 6-class logits = relu(acc+bias) @ W2 + b2.
template <int KI, int NT, int ACT, int WB16, int PROJ, int CLS>
__global__ __launch_bounds__(256) void pgemm_kernel(const unsigned short* __restrict__ Ab,
                                                    const unsigned short* __restrict__ Bf,
                                                    const float* __restrict__ bias,
                                                    unsigned short* __restrict__ Cb,
                                                    const float* __restrict__ aps,
                                                    const float* __restrict__ apd,
                                                    float* __restrict__ als,
                                                    float* __restrict__ ald,
                                                    const float* __restrict__ W2,
                                                    const float* __restrict__ b2,
                                                    float* __restrict__ out2,
                                                    int M) {
    constexpr int NW = NT / 4;
    constexpr int K = KI * 64;
    __shared__ __align__(16) unsigned short Als[2][4096];  // 2 x 8KB bf16 64x64 tiles
    int tid = threadIdx.x, wv = tid >> 6, ln = tid & 63;
    int m0 = blockIdx.x * 64;

    int srow[2], scol[2];
#pragma unroll
    for (int i = 0; i < 2; i++) {
        int s = tid + i * 256;
        int r = s >> 3;
        srow[i] = min(m0 + r, M - 1);
        scol[i] = ((s & 7) ^ (r & 7)) * 8;
    }

    floatx4 acc[4][NW] = {};
    short8 breg[2][NW * 2];
    int4 ai0[2], ai1[2];

    auto issueA = [&](int k, int4* ai) {
#pragma unroll
        for (int i = 0; i < 2; i++)
            ai[i] = *(const int4*)(Ab + (size_t)srow[i] * K + k * 64 + scol[i]);
    };
    auto issueB = [&](int k, short8* b) {
#pragma unroll
        for (int nw = 0; nw < NW; nw++)
#pragma unroll
            for (int ks = 0; ks < 2; ks++)
                b[nw * 2 + ks] = *(const short8*)(
                    Bf + ((((size_t)k * NT + (wv * NW + nw)) * 2 + ks) * 64 + ln) * 8);
    };
    auto writeA = [&](int k, const int4* ai) {
        unsigned short* dst = &Als[k & 1][0];
#pragma unroll
        for (int i = 0; i < 2; i++) *(int4*)&dst[(tid + i * 256) * 8] = ai[i];
    };
    auto compute = [&](int k, const short8* b) {
        const unsigned short* src = &Als[k & 1][0];
#pragma unroll
        for (int ks = 0; ks < 2; ks++) {
            short8 a[4];
#pragma unroll
            for (int mt = 0; mt < 4; mt++) {
                int row = mt * 16 + (ln & 15);
                int g = ks * 4 + (ln >> 4);
                a[mt] = *(const short8*)&src[row * 64 + (g ^ (row & 7)) * 8];
            }
#pragma unroll
            for (int nw = 0; nw < NW; nw++)
#pragma unroll
                for (int mt = 0; mt < 4; mt++)
                    acc[mt][nw] = __builtin_amdgcn_mfma_f32_16x16x32_bf16(
                        a[mt], b[nw * 2 + ks], acc[mt][nw], 0, 0, 0);
        }
    };

    issueA(0, ai0);
    issueB(0, breg[0]);
    writeA(0, ai0);
    WAIT_LGKM0();
    __builtin_amdgcn_s_barrier();

#pragma unroll
    for (int kk = 0; kk < KI / 2; kk++) {
        int k = kk * 2;
        issueA(k + 1, ai1);
        issueB(k + 1, breg[1]);
        compute(k, breg[0]);
        writeA(k + 1, ai1);
        WAIT_LGKM0();
        __builtin_amdgcn_s_barrier();
        if (k + 2 < KI) {
            issueA(k + 2, ai0);
            issueB(k + 2, breg[0]);
        }
        compute(k + 1, breg[1]);
        if (k + 2 < KI) {
            writeA(k + 2, ai0);
            WAIT_LGKM0();
            __builtin_amdgcn_s_barrier();
        }
    }

    constexpr int Nout = NT * 16;
    // main C store (C/D layout: col=lane&15, row=(lane>>4)*4+reg)
    if constexpr (WB16) {
#pragma unroll
        for (int mt = 0; mt < 4; mt++) {
#pragma unroll
            for (int nw = 0; nw < NW; nw++) {
                int col = (wv * NW + nw) * 16 + (ln & 15);
                int rb = m0 + mt * 16 + (ln >> 4) * 4;
                float bi = bias ? bias[col] : 0.f;
#pragma unroll
                for (int r = 0; r < 4; r++) {
                    int row = rb + r;
                    if (row < M) {
                        float v = acc[mt][nw][r] + bi;
                        if (ACT) v = fmaxf(v, 0.f);
                        Cb[(size_t)row * Nout + col] = f2b(v);
                    }
                }
            }
        }
    }

    // fused attention-logit projection: wave wv == head wv (cols wv*64..wv*64+63)
    if constexpr (PROJ) {
        float avs[NW], avd[NW];
#pragma unroll
        for (int nw = 0; nw < NW; nw++) {
            int d = nw * 16 + (ln & 15);
            avs[nw] = aps[wv * DHD + d];
            avd[nw] = apd[wv * DHD + d];
        }
#pragma unroll
        for (int mt = 0; mt < 4; mt++) {
#pragma unroll
            for (int r = 0; r < 4; r++) {
                float ssum = 0.f, dsum = 0.f;
#pragma unroll
                for (int nw = 0; nw < NW; nw++) {
                    float v = acc[mt][nw][r];
                    ssum = fmaf(v, avs[nw], ssum);
                    dsum = fmaf(v, avd[nw], dsum);
                }
#pragma unroll
                for (int m = 8; m > 0; m >>= 1) {
                    ssum += __shfl_xor(ssum, m, 16);
                    dsum += __shfl_xor(dsum, m, 16);
                }
                int row = m0 + mt * 16 + (ln >> 4) * 4 + r;
                if ((ln & 15) == 0 && row < M) {
                    als[row * 4 + wv] = ssum;
                    ald[row * 4 + wv] = dsum;
                }
            }
        }
    }

    // fused tiny classifier: logits = relu(acc+bias) @ W2[Nout][6] + b2
    if constexpr (CLS) {
        __shared__ float cred[64][4][NCLS];
        float w2[NW][NCLS];
#pragma unroll
        for (int nw = 0; nw < NW; nw++) {
            int col = (wv * NW + nw) * 16 + (ln & 15);
#pragma unroll
            for (int c = 0; c < NCLS; c++) w2[nw][c] = W2[col * NCLS + c];
        }
#pragma unroll
        for (int mt = 0; mt < 4; mt++) {
#pragma unroll
            for (int r = 0; r < 4; r++) {
                float p[NCLS] = {};
#pragma unroll
                for (int nw = 0; nw < NW; nw++) {
                    int col = (wv * NW + nw) * 16 + (ln & 15);
                    float v = fmaxf(acc[mt][nw][r] + bias[col], 0.f);
#pragma unroll
                    for (int c = 0; c < NCLS; c++) p[c] = fmaf(v, w2[nw][c], p[c]);
                }
#pragma unroll
                for (int m = 8; m > 0; m >>= 1)
#pragma unroll
                    for (int c = 0; c < NCLS; c++) p[c] += __shfl_xor(p[c], m, 16);
                int rl = mt * 16 + (ln >> 4) * 4 + r;
                if ((ln & 15) == 0)
#pragma unroll
                    for (int c = 0; c < NCLS; c++) cred[rl][wv][c] = p[c];
            }
        }
        __syncthreads();
        for (int t = tid; t < 64 * NCLS; t += 256) {
            int row = t / NCLS, c = t % NCLS;
            if (m0 + row < M) {
                float s = cred[row][0][c] + cred[row][1][c] + cred[row][2][c] +
                          cred[row][3][c] + b2[c];
                out2[(size_t)(m0 + row) * NCLS + c] = s;
            }
        }
    }
}

// ---------------- wave-per-node, single-pass edge softmax + aggregation + LN + ReLU + residual ----
// Half-wave per edge: lanes 0-31 take even edge slots, lanes 32-63 odd slots.
// Each lane owns 8 feature dims (j*8..j*8+7) via one ushort8 (16B) load per edge.
// Denominator fused into the gather pass, normalized once in the epilogue.
__global__ __launch_bounds__(256) void agg_ln_kernel(const int* __restrict__ rowptr,
                                                     const int* __restrict__ csr,
                                                     const float* __restrict__ al_s,
                                                     const float* __restrict__ al_d,
                                                     const unsigned short* __restrict__ xhb,
                                                     const float* __restrict__ bgat,
                                                     const float* __restrict__ g,
                                                     const float* __restrict__ bb,
                                                     float* __restrict__ h,
                                                     unsigned short* __restrict__ hb) {
    int wv = threadIdx.x >> 6, ln = threadIdx.x & 63;
    int n = blockIdx.x * 4 + wv;
    if (n >= NN) return;
    int start = rowptr[n], end = rowptr[n + 1];
    int half = ln >> 5;   // which edge-parity this lane handles
    int j = ln & 31;      // feature-dim group: dims j*8..j*8+7
    int head = j >> 3;    // 0..3
    float adh = al_d[n * 4 + head];

    float p[8] = {}, q[8] = {};
    float dsp = 0.f, dsq = 0.f;

    int i = start + half;
    for (; i + 2 < end; i += 4) {
        int s0 = csr[i], s1 = csr[i + 2];
        float e0 = al_s[s0 * 4 + head] + adh; e0 = e0 > 0.f ? e0 : NEG * e0;
        float e1 = al_s[s1 * 4 + head] + adh; e1 = e1 > 0.f ? e1 : NEG * e1;
        float w0 = __expf(e0), w1 = __expf(e1);
        dsp += w0; dsq += w1;
        short8 u0 = *(const short8*)&xhb[(size_t)s0 * HID + j * 8];
        short8 u1 = *(const short8*)&xhb[(size_t)s1 * HID + j * 8];
#pragma unroll
        for (int k = 0; k < 8; k++) {
            p[k] = fmaf(w0, b2f((unsigned short)u0[k]), p[k]);
            q[k] = fmaf(w1, b2f((unsigned short)u1[k]), q[k]);
        }
    }
    if (i < end) {
        int s0 = csr[i];
        float e0 = al_s[s0 * 4 + head] + adh; e0 = e0 > 0.f ? e0 : NEG * e0;
        float w0 = __expf(e0);
        dsp += w0;
        short8 u0 = *(const short8*)&xhb[(size_t)s0 * HID + j * 8];
#pragma unroll
        for (int k = 0; k < 8; k++) p[k] = fmaf(w0, b2f((unsigned short)u0[k]), p[k]);
    }

    // combine the two edge-parity halves (per-head denominator + per-dim sums)
    float ds = dsp + dsq;
    ds += __shfl_xor(ds, 32, 64);
    float inv = 1.f / ds;

    const float4* bgp = (const float4*)&bgat[j * 8];
    float4 bg0 = bgp[0], bg1 = bgp[1];
    float bgk[8] = {bg0.x, bg0.y, bg0.z, bg0.w, bg1.x, bg1.y, bg1.z, bg1.w};

    float vv[8];
    float ps = 0.f, ps2 = 0.f;
#pragma unroll
    for (int k = 0; k < 8; k++) {
        float t = p[k] + q[k];
        t += __shfl_xor(t, 32, 64);
        float val = t * inv + bgk[k];
        vv[k] = val;
        ps += val;
        ps2 = fmaf(val, val, ps2);
    }
    // wave LN reduce: halves are identical after the 32-swap, reduce within 32 lanes
#pragma unroll
    for (int off = 16; off > 0; off >>= 1) {
        ps += __shfl_xor(ps, off, 64);
        ps2 += __shfl_xor(ps2, off, 64);
    }
    float mu = ps * (1.f / HID);
    float var = ps2 * (1.f / HID) - mu * mu;
    float rs = rsqrtf(var + LNEPS);

    const float4* gp = (const float4*)&g[j * 8];
    const float4* bp = (const float4*)&bb[j * 8];
    float4 g0 = gp[0], g1 = gp[1];
    float4 c0 = bp[0], c1 = bp[1];
    float gk[8] = {g0.x, g0.y, g0.z, g0.w, g1.x, g1.y, g1.z, g1.w};
    float ck[8] = {c0.x, c0.y, c0.z, c0.w, c1.x, c1.y, c1.z, c1.w};

    size_t idx = (size_t)n * HID + j * 8;
    const float4* hp = (const float4*)&h[idx];
    float4 h0 = hp[0], h1 = hp[1];
    float hk[8] = {h0.x, h0.y, h0.z, h0.w, h1.x, h1.y, h1.z, h1.w};

    float nh[8];
#pragma unroll
    for (int k = 0; k < 8; k++) {
        float o = fmaxf((vv[k] - mu) * rs * gk[k] + ck[k], 0.f);
        nh[k] = hk[k] + o;
    }

    if (half == 0) {
        ((float4*)&h[idx])[0] = make_float4(nh[0], nh[1], nh[2], nh[3]);
        ((float4*)&h[idx])[1] = make_float4(nh[4], nh[5], nh[6], nh[7]);
    } else {
        unsigned short ub[8];
#pragma unroll
        for (int k = 0; k < 8; k++) ub[k] = f2b(nh[k]);
        *(int4*)&hb[idx] = *(const int4*)ub;
    }
}

extern "C" void kernel_launch(void* const* d_in, const int* in_sizes, int n_in,
                              void* d_out, int out_size, void* d_ws, size_t ws_size,
                              hipStream_t stream) {
    const float* x    = (const float*)d_in[0];
    const int*   ei   = (const int*)d_in[1];
    const float* W_in = (const float*)d_in[2];
    const float* b_in = (const float*)d_in[3];
    const float* W_gat[2]   = {(const float*)d_in[4],  (const float*)d_in[10]};
    const float* att_src[2] = {(const float*)d_in[5],  (const float*)d_in[11]};
    const float* att_dst[2] = {(const float*)d_in[6],  (const float*)d_in[12]};
    const float* b_gat[2]   = {(const float*)d_in[7],  (const float*)d_in[13]};
    const float* ln_g[2]    = {(const float*)d_in[8],  (const float*)d_in[14]};
    const float* ln_b[2]    = {(const float*)d_in[9],  (const float*)d_in[15]};
    const float* W_c1 = (const float*)d_in[16];
    const float* b_c1 = (const float*)d_in[17];
    const float* W_c2 = (const float*)d_in[18];
    const float* b_c2 = (const float*)d_in[19];

    char* ws = (char*)d_ws;
    size_t off = 0;
    auto alloc = [&](size_t bytes) -> void* {
        void* p = ws + off;
        off += (bytes + 255) & ~(size_t)255;
        return p;
    };
    float*          h   = (float*)alloc((size_t)NN * HID * 4);
    unsigned short* hb  = (unsigned short*)alloc((size_t)NN * HID * 2);
    unsigned short* xhb = (unsigned short*)alloc((size_t)NN * HID * 2);
    float* al_s = (float*)alloc((size_t)NN * HEADS * 4);
    float* al_d = (float*)alloc((size_t)NN * HEADS * 4);
    int* rowptr  = (int*)alloc((size_t)(NN + 1) * 4);
    int* cursor  = (int*)alloc((size_t)NN * 4);
    int* csr     = (int*)alloc((size_t)(EE + NN) * 4);
    int* scanned = (int*)alloc((size_t)NN * 4);
    int* chtot   = (int*)alloc(64 * 4);
    unsigned short* WinF = (unsigned short*)alloc((size_t)HID * INDIM * 2);
    unsigned short* WgF0 = (unsigned short*)alloc((size_t)HID * HID * 2);
    unsigned short* WgF1 = (unsigned short*)alloc((size_t)HID * HID * 2);
    unsigned short* Wc1F = (unsigned short*)alloc((size_t)(HID / 2) * HID * 2);
    unsigned short* WgF[2] = {WgF0, WgF1};

    const int* srcv = ei;
    const int* dstv = ei + EE;

    // weight packs (fp32 [K][N] -> bf16 MFMA B-fragment order)
    pack_w_kernel<<<(INDIM * HID / 8 + 255) / 256, 256, 0, stream>>>(W_in, WinF, INDIM, HID);
    pack_w_kernel<<<(HID * HID / 8 + 255) / 256, 256, 0, stream>>>(W_gat[0], WgF0, HID, HID);
    pack_w_kernel<<<(HID * HID / 8 + 255) / 256, 256, 0, stream>>>(W_gat[1], WgF1, HID, HID);
    pack_w_kernel<<<(HID * (HID / 2) / 8 + 255) / 256, 256, 0, stream>>>(W_c1, Wc1F, HID, HID / 2);

    // CSR build
    int nch = (NN + 1023) / 1024;
    init_cnt_kernel<<<(NN + 255) / 256, 256, 0, stream>>>(cursor);
    count_edges_kernel<<<(EE + 255) / 256, 256, 0, stream>>>(dstv, cursor);
    scan1_kernel<<<nch, 1024, 0, stream>>>(cursor, scanned, chtot, NN);
    scan2_kernel<<<1, 64, 0, stream>>>(chtot, nch);
    scan3_kernel<<<(NN + 255) / 256, 256, 0, stream>>>(scanned, chtot, rowptr, NN);
    copyfill_kernel<<<(NN + 255) / 256, 256, 0, stream>>>(rowptr, cursor, csr);
    scatter_edges_kernel<<<(EE + 255) / 256, 256, 0, stream>>>(srcv, dstv, cursor, csr);

    // h = relu(x @ W_in + b_in): dedicated MT=128 fp32-A kernel
    inproj_kernel<<<(NN + 127) / 128, 256, 0, stream>>>(x, WinF, b_in, h, hb);

    int MB64 = (NN + 63) / 64;  // 782
    for (int l = 0; l < 2; l++) {
        // xh = h @ W_gat (bf16 out) + fused al_src/al_dst projection
        pgemm_kernel<4, 16, 0, 1, 1, 0><<<MB64, 256, 0, stream>>>(
            hb, WgF[l], nullptr, xhb,
            att_src[l], att_dst[l], al_s, al_d, nullptr, nullptr, nullptr, NN);
        agg_ln_kernel<<<(NN + 3) / 4, 256, 0, stream>>>(rowptr, csr, al_s, al_d, xhb,
                                                        b_gat[l], ln_g[l], ln_b[l], h, hb);
    }

    // classifier: logits = relu(h @ W_c1 + b_c1) @ W_c2 + b_c2, fully fused
    pgemm_kernel<4, 8, 1, 0, 0, 1><<<MB64, 256, 0, stream>>>(
        hb, Wc1F, b_c1, nullptr,
        nullptr, nullptr, nullptr, nullptr, W_c2, b_c2, (float*)d_out, NN);
}